// Round 12
// baseline (235.157 us; speedup 1.0000x reference)
//
#include <hip/hip_runtime.h>

#define DIM 1024
#define NH 16
#define NKV 4
#define HD 64
#define INTER 2688
#define BB 2
#define NN 2048
#define MM (BB*NN)

typedef __attribute__((ext_vector_type(4))) float f32x4;
typedef __attribute__((ext_vector_type(16))) float f32x16;
typedef __attribute__((ext_vector_type(8))) short short8;

#define CROW(r,h) ((((r)&3)) + 8*((r)>>2) + 4*(h))

__device__ __forceinline__ unsigned short f2bf(float f) {
  union { float f; unsigned u; } v; v.f = f;
  unsigned r = v.u + 0x7fffu + ((v.u >> 16) & 1u);
  return (unsigned short)(r >> 16);
}
__device__ __forceinline__ float bf2f(unsigned short u) {
  union { unsigned u; float f; } v; v.u = ((unsigned)u) << 16; return v.f;
}
__device__ __forceinline__ float ld_res(const float* p) { return *p; }
__device__ __forceinline__ float ld_res(const unsigned short* p) { return bf2f(*p); }
__device__ __forceinline__ void st_out(float* p, float v) { *p = v; }
__device__ __forceinline__ void st_out(unsigned short* p, float v) { *p = f2bf(v); }

// async global->LDS, 16B per lane; LDS dest = wave-uniform base + lane*16
__device__ __forceinline__ void glds16(const unsigned short* g, unsigned short* l) {
  __builtin_amdgcn_global_load_lds(
      (const __attribute__((address_space(1))) void*)g,
      (__attribute__((address_space(3))) void*)l, 16, 0, 0);
}

// XCD-aware block remap (requires gridDim.x*gridDim.y % 8 == 0; bijective).
__device__ __forceinline__ void xcd_map(int& bx, int& by) {
  int gx = gridDim.x;
  int nwg = gx * gridDim.y;
  int bid = (int)blockIdx.y * gx + (int)blockIdx.x;
  int cpx = nwg >> 3;
  int lg = (bid & 7) * cpx + (bid >> 3);
  bx = lg % gx;
  by = lg / gx;
}

// ---------------- merged weight transpose: fp32 [K][Nc] -> bf16 [Nc][K] -------------
__global__ void transpose_all(const float* __restrict__ Wq, const float* __restrict__ Wkv,
                              const float* __restrict__ Wo, const float* __restrict__ W1,
                              const float* __restrict__ W3, const float* __restrict__ W2,
                              unsigned short* __restrict__ WqkvT, unsigned short* __restrict__ WoT,
                              unsigned short* __restrict__ W1T, unsigned short* __restrict__ W3T,
                              unsigned short* __restrict__ W2T) {
  int tb = blockIdx.x;
  const float* src; unsigned short* dst; int K, Nc, t0;
  if (tb < 1024)        { src = Wq;  dst = WqkvT;                         K = 1024; Nc = 1024; t0 = tb; }
  else if (tb < 1536)   { src = Wkv; dst = WqkvT + (size_t)1024 * 1024;   K = 1024; Nc = 512;  t0 = tb - 1024; }
  else if (tb < 2560)   { src = Wo;  dst = WoT;                           K = 1024; Nc = 1024; t0 = tb - 1536; }
  else if (tb < 5248)   { src = W1;  dst = W1T;                           K = 1024; Nc = 2688; t0 = tb - 2560; }
  else if (tb < 7936)   { src = W3;  dst = W3T;                           K = 1024; Nc = 2688; t0 = tb - 5248; }
  else                  { src = W2;  dst = W2T;                           K = 2688; Nc = 1024; t0 = tb - 7936; }
  int ntx = Nc >> 5;
  int n0 = (t0 % ntx) * 32, k0 = (t0 / ntx) * 32;
  __shared__ float tile[32][33];
  int tx = threadIdx.x & 31, ty = threadIdx.x >> 5;
#pragma unroll
  for (int i = 0; i < 32; i += 8)
    tile[ty + i][tx] = src[(size_t)(k0 + ty + i) * Nc + n0 + tx];
  __syncthreads();
#pragma unroll
  for (int i = 0; i < 32; i += 8)
    dst[(size_t)(n0 + ty + i) * K + k0 + tx] = f2bf(tile[tx][ty + i]);
}

// ---------------- RMSNorm: [rows][1024] (fp32 or bf16 in) -> bf16 ----------------
template <typename InT>
__global__ void rmsnorm_k(const InT* __restrict__ x, const float* __restrict__ w,
                          unsigned short* __restrict__ h) {
  int row = blockIdx.x;
  int t = threadIdx.x;
  float4 v;
  if constexpr (sizeof(InT) == 4) {
    v = ((const float4*)(x + (size_t)row * DIM))[t];
  } else {
    ushort4 u = ((const ushort4*)(x + (size_t)row * DIM))[t];
    v.x = bf2f(u.x); v.y = bf2f(u.y); v.z = bf2f(u.z); v.w = bf2f(u.w);
  }
  float ss = v.x * v.x + v.y * v.y + v.z * v.z + v.w * v.w;
#pragma unroll
  for (int o = 1; o < 64; o <<= 1) ss += __shfl_xor(ss, o);
  __shared__ float ps[4];
  if ((t & 63) == 0) ps[t >> 6] = ss;
  __syncthreads();
  float r = rsqrtf((ps[0] + ps[1] + ps[2] + ps[3]) * (1.0f / DIM) + 1e-6f);
  float4 wv = ((const float4*)w)[t];
  ushort4 o4;
  o4.x = f2bf(v.x * r * wv.x);
  o4.y = f2bf(v.y * r * wv.y);
  o4.z = f2bf(v.z * r * wv.z);
  o4.w = f2bf(v.w * r * wv.w);
  *(ushort4*)(h + (size_t)row * DIM + t * 4) = o4;
}

// ---------------- GEMM64 v2: BM=64 x BN=128, BK=64, 2-phase glds dbuf ----------------
template <typename ResT, typename OutT>
__global__ __launch_bounds__(256, 3) void gemm64(
    const unsigned short* __restrict__ A, const unsigned short* __restrict__ Bt,
    const ResT* __restrict__ res, OutT* __restrict__ C, int Nc, int K) {
  __shared__ __align__(16) unsigned short Asm[2][64 * 64];
  __shared__ __align__(16) unsigned short Bsm[2][128 * 64];
  int tid = threadIdx.x;
  int w = tid >> 6, l = tid & 63;
  int bx, by;
  xcd_map(bx, by);
  int bm = by * 64, bn = bx * 128;
  int wc = w * 32;
  int c0 = l & 15, g = l >> 4;

  int sra = w * 16 + (l >> 3);
  int srb = w * 32 + (l >> 3);
  int schA = ((l & 7) ^ (l >> 3)) * 8;
  const unsigned short* gA = A + (size_t)(bm + sra) * K + schA;
  const unsigned short* gB = Bt + (size_t)(bn + srb) * K + schA;
  int lsa = (w * 16) * 64, lsb = (w * 32) * 64;

  f32x4 acc[4][2] = {};
  int T = K / 64;
  glds16(gA, &Asm[0][lsa]);
  glds16(gA + 8 * K, &Asm[0][lsa + 8 * 64]);
  glds16(gB, &Bsm[0][lsb]);
  glds16(gB + 8 * K, &Bsm[0][lsb + 8 * 64]);
  glds16(gB + 16 * K, &Bsm[0][lsb + 16 * 64]);
  glds16(gB + 24 * K, &Bsm[0][lsb + 24 * 64]);
  __syncthreads();
  int buf = 0;
  for (int s = 0; s < T; ++s) {
    int nb = buf ^ 1;
    if (s + 1 < T) {
      int ko = (s + 1) * 64;
      glds16(gA + ko, &Asm[nb][lsa]);
      glds16(gA + 8 * K + ko, &Asm[nb][lsa + 8 * 64]);
      glds16(gB + ko, &Bsm[nb][lsb]);
      glds16(gB + 8 * K + ko, &Bsm[nb][lsb + 8 * 64]);
      glds16(gB + 16 * K + ko, &Bsm[nb][lsb + 16 * 64]);
      glds16(gB + 24 * K + ko, &Bsm[nb][lsb + 24 * 64]);
    }
    const unsigned short* As = Asm[buf];
    const unsigned short* Bs = Bsm[buf];
#pragma unroll
    for (int ks = 0; ks < 2; ++ks) {
      short8 af[4], bf[2];
#pragma unroll
      for (int m = 0; m < 4; m++) {
        int ra = m * 16 + c0;
        af[m] = *(const short8*)&As[ra * 64 + (((ks * 4 + g) ^ (ra & 7)) * 8)];
      }
#pragma unroll
      for (int n = 0; n < 2; n++) {
        int rb = wc + n * 16 + c0;
        bf[n] = *(const short8*)&Bs[rb * 64 + (((ks * 4 + g) ^ (rb & 7)) * 8)];
      }
      __builtin_amdgcn_s_setprio(1);
#pragma unroll
      for (int m = 0; m < 4; m++)
#pragma unroll
        for (int n = 0; n < 2; n++)
          acc[m][n] = __builtin_amdgcn_mfma_f32_16x16x32_bf16(af[m], bf[n], acc[m][n], 0, 0, 0);
      __builtin_amdgcn_s_setprio(0);
    }
    __syncthreads();
    buf = nb;
  }
  int gq = l >> 4;
#pragma unroll
  for (int m = 0; m < 4; m++) {
#pragma unroll
    for (int i = 0; i < 4; i++) {
      int row = bm + m * 16 + gq * 4 + i;
#pragma unroll
      for (int n = 0; n < 2; n++) {
        int col = bn + wc + n * 16 + c0;
        float v = acc[m][n][i] + ld_res(&res[(size_t)row * Nc + col]);
        st_out(&C[(size_t)row * Nc + col], v);
      }
    }
  }
}

// ---------------- QKV GEMM (BK=64) with fused RoPE epilogue ----------------
__global__ __launch_bounds__(256, 3) void gemm_qkv(
    const unsigned short* __restrict__ A, const unsigned short* __restrict__ Bt,
    const float* __restrict__ cosb, const float* __restrict__ sinb,
    unsigned short* __restrict__ qb, unsigned short* __restrict__ kb,
    unsigned short* __restrict__ vtb) {
  const int K = 1024;
  const float QS = 0.125f * 1.44269504f;
  __shared__ __align__(16) unsigned short Asm[2][64 * 64];
  __shared__ __align__(16) unsigned short Bsm[2][128 * 64];
  int tid = threadIdx.x;
  int w = tid >> 6, l = tid & 63;
  int bx, by;
  xcd_map(bx, by);
  int bm = by * 64, bn = bx * 128;
  int wc = w * 32;
  int c0 = l & 15, g = l >> 4;

  int sra = w * 16 + (l >> 3);
  int srb = w * 32 + (l >> 3);
  int schA = ((l & 7) ^ (l >> 3)) * 8;
  const unsigned short* gA = A + (size_t)(bm + sra) * K + schA;
  const unsigned short* gB = Bt + (size_t)(bn + srb) * K + schA;
  int lsa = (w * 16) * 64, lsb = (w * 32) * 64;

  f32x4 acc[4][2] = {};
  int T = K / 64;
  glds16(gA, &Asm[0][lsa]);
  glds16(gA + 8 * K, &Asm[0][lsa + 8 * 64]);
  glds16(gB, &Bsm[0][lsb]);
  glds16(gB + 8 * K, &Bsm[0][lsb + 8 * 64]);
  glds16(gB + 16 * K, &Bsm[0][lsb + 16 * 64]);
  glds16(gB + 24 * K, &Bsm[0][lsb + 24 * 64]);
  __syncthreads();
  int buf = 0;
  for (int s = 0; s < T; ++s) {
    int nb = buf ^ 1;
    if (s + 1 < T) {
      int ko = (s + 1) * 64;
      glds16(gA + ko, &Asm[nb][lsa]);
      glds16(gA + 8 * K + ko, &Asm[nb][lsa + 8 * 64]);
      glds16(gB + ko, &Bsm[nb][lsb]);
      glds16(gB + 8 * K + ko, &Bsm[nb][lsb + 8 * 64]);
      glds16(gB + 16 * K + ko, &Bsm[nb][lsb + 16 * 64]);
      glds16(gB + 24 * K + ko, &Bsm[nb][lsb + 24 * 64]);
    }
    const unsigned short* As = Asm[buf];
    const unsigned short* Bs = Bsm[buf];
#pragma unroll
    for (int ks = 0; ks < 2; ++ks) {
      short8 af[4], bf[2];
#pragma unroll
      for (int m = 0; m < 4; m++) {
        int ra = m * 16 + c0;
        af[m] = *(const short8*)&As[ra * 64 + (((ks * 4 + g) ^ (ra & 7)) * 8)];
      }
#pragma unroll
      for (int n = 0; n < 2; n++) {
        int rb = wc + n * 16 + c0;
        bf[n] = *(const short8*)&Bs[rb * 64 + (((ks * 4 + g) ^ (rb & 7)) * 8)];
      }
      __builtin_amdgcn_s_setprio(1);
#pragma unroll
      for (int m = 0; m < 4; m++)
#pragma unroll
        for (int n = 0; n < 2; n++)
          acc[m][n] = __builtin_amdgcn_mfma_f32_16x16x32_bf16(af[m], bf[n], acc[m][n], 0, 0, 0);
      __builtin_amdgcn_s_setprio(0);
    }
    __syncthreads();
    buf = nb;
  }
  int gq = l >> 4;
  int lodd = c0 & 1;
#pragma unroll
  for (int m = 0; m < 4; m++) {
#pragma unroll
    for (int i = 0; i < 4; i++) {
      int row = bm + m * 16 + gq * 4 + i;
      int b = row >> 11, tok = row & (NN - 1);
#pragma unroll
      for (int n = 0; n < 2; n++) {
        int col = bn + wc + n * 16 + c0;
        float val = acc[m][n][i];
        float partner = __shfl_xor(val, 1);
        if (bn < 1024) {
          int head = col >> 6, d = col & 63, j = d >> 1;
          float c = cosb[tok * 32 + j], s = sinb[tok * 32 + j];
          float r = lodd ? (partner * s + val * c) : (val * c - partner * s);
          qb[(((size_t)(b * NH + head)) * NN + tok) * 64 + d] = f2bf(r * QS);
        } else if (bn < 1280) {
          int cc = col - 1024;
          int kvh = cc >> 6, d = cc & 63, j = d >> 1;
          float c = cosb[tok * 32 + j], s = sinb[tok * 32 + j];
          float r = lodd ? (partner * s + val * c) : (val * c - partner * s);
          kb[(((size_t)(b * NKV + kvh)) * NN + tok) * 64 + d] = f2bf(r);
        } else {
          int cc = col - 1280;
          int kvh = cc >> 6, d = cc & 63;
          vtb[(((size_t)(b * NKV + kvh)) * 64 + d) * NN + tok] = f2bf(val);
        }
      }
    }
  }
}

// ---------------- fused FFN13 v6: 8-phase-style counted-vmcnt template ----------------
// BM=128 x BN=128(of each W1,W3), 512 thr (8 waves 2Mx4N), BK=64, 3-buffer LDS
// rotation (144KB, 1 block/CU, 2 waves/SIMD). 4 phases/K-tile:
// {ds_read subtile | 2 glds for tile t+2 -> s_barrier -> lgkmcnt(0)+schedbar ->
//  setprio(1) 8 MFMA setprio(0)}; vmcnt(6) ONCE per tile (never 0 in loop).
__global__ __launch_bounds__(512, 2) void gemm_ffn13(
    const unsigned short* __restrict__ A, const unsigned short* __restrict__ B1t,
    const unsigned short* __restrict__ B3t, unsigned short* __restrict__ G,
    int Nc, int K) {
  __shared__ __align__(16) unsigned short Asm[3][128 * 64];
  __shared__ __align__(16) unsigned short B1sm[3][128 * 64];
  __shared__ __align__(16) unsigned short B3sm[3][128 * 64];
  int tid = threadIdx.x;
  int w = tid >> 6, l = tid & 63;
  // XCD rect map: grid 672 = 8 xcd x (21 bx x 4 by); by-inner (B-tile reused 4x)
  int bid = (int)blockIdx.x;
  int xcd = bid & 7, r = bid >> 3;           // r in [0,84)
  int bx = r >> 2, by = (xcd << 2) + (r & 3);
  int bm = by * 128, bn = bx * 128;
  int wm = w >> 2, wn = w & 3;
  int c0 = l & 15, g = l >> 4;

  // staging: wave w stages rows [w*16, w*16+16) of A, B1, B3 (2 glds calls each)
  int lr = l >> 3;
  int sch = ((l & 7) ^ lr) * 8;              // inverse-swizzled source chunk
  const unsigned short* gA  = A   + (size_t)(bm + w * 16 + lr) * K + sch;
  const unsigned short* gB1 = B1t + (size_t)(bn + w * 16 + lr) * K + sch;
  const unsigned short* gB3 = B3t + (size_t)(bn + w * 16 + lr) * K + sch;
  int ls = (w * 16) * 64;

  f32x4 a1[4][2] = {};
  f32x4 a3[4][2] = {};
  const int T = K / 64;

  // prologue: stage tiles 0,1 into bufs 0,1 (6 calls each)
#pragma unroll
  for (int p = 0; p < 2; ++p) {
    int ko = p * 64;
    glds16(gA + ko, &Asm[p][ls]);
    glds16(gA + 8 * K + ko, &Asm[p][ls + 512]);
    glds16(gB1 + ko, &B1sm[p][ls]);
    glds16(gB1 + 8 * K + ko, &B1sm[p][ls + 512]);
    glds16(gB3 + ko, &B3sm[p][ls]);
    glds16(gB3 + 8 * K + ko, &B3sm[p][ls + 512]);
  }
  asm volatile("s_waitcnt vmcnt(6)" ::: "memory");   // tile 0 landed
  asm volatile("s_barrier" ::: "memory");

  int cur = 0;
  for (int t = 0; t < T; ++t) {
    int nx = cur + 2; if (nx >= 3) nx -= 3;
    bool pre = (t + 2 < T);
    int ko = (t + 2) * 64;
    const unsigned short* As  = Asm[cur];
    const unsigned short* B1s = B1sm[cur];
    const unsigned short* B3s = B3sm[cur];
    short8 af[4], bf[2];

    // ---- phase 0 (ks=0): read af + b1f; glds A(t+2)
#pragma unroll
    for (int m = 0; m < 4; m++) {
      int ra = wm * 64 + m * 16 + c0;
      af[m] = *(const short8*)&As[ra * 64 + ((g ^ (ra & 7)) * 8)];
    }
#pragma unroll
    for (int n = 0; n < 2; n++) {
      int rb = wn * 32 + n * 16 + c0;
      bf[n] = *(const short8*)&B1s[rb * 64 + ((g ^ (rb & 7)) * 8)];
    }
    if (pre) { glds16(gA + ko, &Asm[nx][ls]); glds16(gA + 8 * K + ko, &Asm[nx][ls + 512]); }
    asm volatile("s_barrier" ::: "memory");
    asm volatile("s_waitcnt lgkmcnt(0)" ::: "memory");
    __builtin_amdgcn_sched_barrier(0);
    __builtin_amdgcn_s_setprio(1);
#pragma unroll
    for (int m = 0; m < 4; m++)
#pragma unroll
      for (int n = 0; n < 2; n++)
        a1[m][n] = __builtin_amdgcn_mfma_f32_16x16x32_bf16(af[m], bf[n], a1[m][n], 0, 0, 0);
    __builtin_amdgcn_s_setprio(0);

    // ---- phase 1 (ks=0): read b3f; glds B1(t+2)
#pragma unroll
    for (int n = 0; n < 2; n++) {
      int rb = wn * 32 + n * 16 + c0;
      bf[n] = *(const short8*)&B3s[rb * 64 + ((g ^ (rb & 7)) * 8)];
    }
    if (pre) { glds16(gB1 + ko, &B1sm[nx][ls]); glds16(gB1 + 8 * K + ko, &B1sm[nx][ls + 512]); }
    asm volatile("s_barrier" ::: "memory");
    asm volatile("s_waitcnt lgkmcnt(0)" ::: "memory");
    __builtin_amdgcn_sched_barrier(0);
    __builtin_amdgcn_s_setprio(1);
#pragma unroll
    for (int m = 0; m < 4; m++)
#pragma unroll
      for (int n = 0; n < 2; n++)
        a3[m][n] = __builtin_amdgcn_mfma_f32_16x16x32_bf16(af[m], bf[n], a3[m][n], 0, 0, 0);
    __builtin_amdgcn_s_setprio(0);

    // ---- phase 2 (ks=1): read af + b1f; glds B3(t+2)
#pragma unroll
    for (int m = 0; m < 4; m++) {
      int ra = wm * 64 + m * 16 + c0;
      af[m] = *(const short8*)&As[ra * 64 + (((4 + g) ^ (ra & 7)) * 8)];
    }
#pragma unroll
    for (int n = 0; n < 2; n++) {
      int rb = wn * 32 + n * 16 + c0;
      bf[n] = *(const short8*)&B1s[rb * 64 + (((4 + g) ^ (rb & 7)) * 8)];
    }
    if (pre) { glds16(gB3 + ko, &B3sm[nx][ls]); glds16(gB3 + 8 * K + ko, &B3sm[nx][ls + 512]); }
    asm volatile("s_barrier" ::: "memory");
    asm volatile("s_waitcnt lgkmcnt(0)" ::: "memory");
    __builtin_amdgcn_sched_barrier(0);
    __builtin_amdgcn_s_setprio(1);
#pragma unroll
    for (int m = 0; m < 4; m++)
#pragma unroll
      for (int n = 0; n < 2; n++)
        a1[m][n] = __builtin_amdgcn_mfma_f32_16x16x32_bf16(af[m], bf[n], a1[m][n], 0, 0, 0);
    __builtin_amdgcn_s_setprio(0);

    // ---- phase 3 (ks=1): read b3f; no glds
#pragma unroll
    for (int n = 0; n < 2; n++) {
      int rb = wn * 32 + n * 16 + c0;
      bf[n] = *(const short8*)&B3s[rb * 64 + (((4 + g) ^ (rb & 7)) * 8)];
    }
    asm volatile("s_barrier" ::: "memory");
    asm volatile("s_waitcnt lgkmcnt(0)" ::: "memory");
    __builtin_amdgcn_sched_barrier(0);
    __builtin_amdgcn_s_setprio(1);
#pragma unroll
    for (int m = 0; m < 4; m++)
#pragma unroll
      for (int n = 0; n < 2; n++)
        a3[m][n] = __builtin_amdgcn_mfma_f32_16x16x32_bf16(af[m], bf[n], a3[m][n], 0, 0, 0);
    __builtin_amdgcn_s_setprio(0);

    // ---- tile end: counted drain (tile t+1 must be landed; t+2's 6 stay in flight)
    if (pre) {
      asm volatile("s_waitcnt vmcnt(6)" ::: "memory");
    } else if (t + 2 == T) {
      asm volatile("s_waitcnt vmcnt(0)" ::: "memory");
    }
    if (t + 1 < T) asm volatile("s_barrier" ::: "memory");
    cur = cur + 1 == 3 ? 0 : cur + 1;
  }

  int gq = l >> 4;
#pragma unroll
  for (int m = 0; m < 4; m++) {
#pragma unroll
    for (int i = 0; i < 4; i++) {
      int row = bm + wm * 64 + m * 16 + gq * 4 + i;
#pragma unroll
      for (int n = 0; n < 2; n++) {
        int col = bn + wn * 32 + n * 16 + c0;
        float x1 = a1[m][n][i], x3 = a3[m][n][i];
        float sg = x1 / (1.0f + __expf(-x1));
        G[(size_t)row * Nc + col] = f2bf(sg * x3);
      }
    }
  }
}

// ---------------- flash attention v5: exp2 domain + defer-max (T13) ----------------
__global__ __launch_bounds__(256, 3) void attn_k(
    const unsigned short* __restrict__ qg_, const unsigned short* __restrict__ kg_,
    const unsigned short* __restrict__ vg_, unsigned short* __restrict__ ob) {
  __shared__ __align__(16) unsigned short Ksm[2][64 * 64];
  __shared__ __align__(16) unsigned short Vsm[2][64 * 64];
  int qb = (blockIdx.z == 0) ? (int)blockIdx.x : ((int)gridDim.x - 1 - (int)blockIdx.x);
  int h = blockIdx.y, b = blockIdx.z;
  int kvh = h & 3;  // jnp.tile semantics
  int tid = threadIdx.x, w = tid >> 6, l = tid & 63;
  int q5 = l & 31, hi = l >> 5;
  int qwbase = qb * 128 + w * 32;
  int qgl = qwbase + q5;

  const unsigned short* Kg = kg_ + ((size_t)(b * NKV + kvh)) * NN * 64;
  const unsigned short* Vg = vg_ + ((size_t)(b * NKV + kvh)) * 64 * NN;

  short8 qf[4];
  {
    const unsigned short* qrow = qg_ + (((size_t)(b * NH + h)) * NN + qgl) * 64 + hi * 8;
#pragma unroll
    for (int d = 0; d < 4; d++) qf[d] = *(const short8*)(qrow + d * 16);
  }

  int srow = l >> 3;
  int schunk = (l & 7) ^ (srow & 7);
  const unsigned short* gK = Kg + (size_t)(w * 16 + srow) * 64 + schunk * 8;
  const unsigned short* gV = Vg + (size_t)(w * 16 + srow) * NN + schunk * 8;

  int nkt = qb * 2 + 2;
  int nkt_w = ((qwbase + 31) >> 6) + 1;

  f32x16 O0 = {}, O1 = {};
  float m_r = -1e30f, l_r = 0.0f;

  glds16(gK, &Ksm[0][w * 1024]);
  glds16(gK + 8 * 64, &Ksm[0][w * 1024 + 512]);
  glds16(gV, &Vsm[0][w * 1024]);
  glds16(gV + 8 * NN, &Vsm[0][w * 1024 + 512]);
  __syncthreads();

  int buf = 0;
  for (int kt = 0; kt < nkt; ++kt) {
    int n0 = kt * 64;
    if (kt + 1 < nkt) {
      int nb = buf ^ 1;
      glds16(gK + (size_t)(n0 + 64) * 64, &Ksm[nb][w * 1024]);
      glds16(gK + (size_t)(n0 + 64) * 64 + 8 * 64, &Ksm[nb][w * 1024 + 512]);
      glds16(gV + n0 + 64, &Vsm[nb][w * 1024]);
      glds16(gV + 8 * NN + n0 + 64, &Vsm[nb][w * 1024 + 512]);
    }
    if (kt < nkt_w) {
      const unsigned short* Ks = Ksm[buf];
      const unsigned short* Vs = Vsm[buf];
      f32x16 S[2];
      __builtin_amdgcn_s_setprio(1);
#pragma unroll
      for (int s = 0; s < 2; s++) {
        f32x16 acc = {};
        int row = s * 32 + q5;
#pragma unroll
        for (int d = 0; d < 4; d++) {
          int ch = (2 * d + hi) ^ (row & 7);
          short8 kf = *(const short8*)&Ks[row * 64 + ch * 8];
          acc = __builtin_amdgcn_mfma_f32_32x32x16_bf16(kf, qf[d], acc, 0, 0, 0);
        }
        S[s] = acc;
      }
      __builtin_amdgcn_s_setprio(0);
      if (kt == nkt_w - 1) {
#pragma unroll
        for (int s = 0; s < 2; s++)
#pragma unroll
          for (int r = 0; r < 16; r++) {
            int kg = n0 + s * 32 + CROW(r, hi);
            S[s][r] = (kg > qgl) ? -1e30f : S[s][r];
          }
      }
      float t16[16];
#pragma unroll
      for (int r = 0; r < 16; r++) t16[r] = fmaxf(S[0][r], S[1][r]);
#pragma unroll
      for (int k = 8; k >= 1; k >>= 1)
#pragma unroll
        for (int r = 0; r < k; r++) t16[r] = fmaxf(t16[r], t16[r + k]);
      float pm = fmaxf(t16[0], __shfl_xor(t16[0], 32));
      if (!__all(pm <= m_r + 8.0f)) {
        float mn = fmaxf(m_r, pm);
        float alpha = exp2f(m_r - mn);
        m_r = mn;
        l_r *= alpha;
        float ab[16];
#pragma unroll
        for (int r = 0; r < 16; r++) ab[r] = __shfl(alpha, CROW(r, 0) + 4 * hi);
#pragma unroll
        for (int r = 0; r < 16; r++) { O0[r] *= ab[r]; O1[r] *= ab[r]; }
      }
#pragma unroll
      for (int s = 0; s < 2; s++)
#pragma unroll
        for (int r = 0; r < 16; r++) S[s][r] = exp2f(S[s][r] - m_r);
      float u[16];
#pragma unroll
      for (int r = 0; r < 16; r++) u[r] = S[0][r] + S[1][r];
#pragma unroll
      for (int k = 8; k >= 1; k >>= 1)
#pragma unroll
        for (int r = 0; r < k; r++) u[r] += u[r + k];
      l_r += (u[0] + __shfl_xor(u[0], 32));
      short8 paf[4];
#pragma unroll
      for (int ks = 0; ks < 4; ks++) {
        const int s = ks >> 1, e = ks & 1;
        unsigned a0, a1, b0, b1;
        asm("v_cvt_pk_bf16_f32 %0, %1, %2" : "=v"(a0) : "v"(S[s][8*e+0]), "v"(S[s][8*e+1]));
        asm("v_cvt_pk_bf16_f32 %0, %1, %2" : "=v"(a1) : "v"(S[s][8*e+2]), "v"(S[s][8*e+3]));
        asm("v_cvt_pk_bf16_f32 %0, %1, %2" : "=v"(b0) : "v"(S[s][8*e+4]), "v"(S[s][8*e+5]));
        asm("v_cvt_pk_bf16_f32 %0, %1, %2" : "=v"(b1) : "v"(S[s][8*e+6]), "v"(S[s][8*e+7]));
        asm("v_permlane32_swap_b32 %0, %1" : "+v"(a0), "+v"(b0));
        asm("v_permlane32_swap_b32 %0, %1" : "+v"(a1), "+v"(b1));
        union { unsigned u4[4]; short8 s8; } pk;
        pk.u4[0] = a0; pk.u4[1] = a1; pk.u4[2] = b0; pk.u4[3] = b1;
        paf[ks] = pk.s8;
      }
      __builtin_amdgcn_s_setprio(1);
#pragma unroll
      for (int ks = 0; ks < 4; ks++) {
        int row0 = q5, row1 = 32 + q5;
        short8 vf0 = *(const short8*)&Vs[row0 * 64 + (((2 * ks + hi) ^ (row0 & 7)) * 8)];
        short8 vf1 = *(const short8*)&Vs[row1 * 64 + (((2 * ks + hi) ^ (row1 & 7)) * 8)];
        O0 = __builtin_amdgcn_mfma_f32_32x32x16_bf16(paf[ks], vf0, O0, 0, 0, 0);
        O1 = __builtin_amdgcn_mfma_f32_32x32x16_bf16(paf[ks], vf1, O1, 0, 0, 0);
      }
      __builtin_amdgcn_s_setprio(0);
    }
    __syncthreads();
    buf ^= 1;
  }
  float linv = 1.0f / l_r;
  float lb[16];
#pragma unroll
  for (int r = 0; r < 16; r++) lb[r] = __shfl(linv, CROW(r, 0) + 4 * hi);
#pragma unroll
  for (int r = 0; r < 16; r++) {
    int orow = qwbase + CROW(r, hi);
    size_t base = ((size_t)b * NN + orow) * 1024 + h * 64 + q5;
    ob[base] = f2bf(O0[r] * lb[r]);
    ob[base + 32] = f2bf(O1[r] * lb[r]);
  }
}

// ---------------- launcher ----------------
extern "C" void kernel_launch(void* const* d_in, const int* in_sizes, int n_in,
                              void* d_out, int out_size, void* d_ws, size_t ws_size,
                              hipStream_t stream) {
  (void)in_sizes; (void)n_in; (void)out_size; (void)ws_size;
  const float* x    = (const float*)d_in[0];
  const float* w_an = (const float*)d_in[1];
  const float* w_fn = (const float*)d_in[2];
  const float* Wq   = (const float*)d_in[3];
  const float* Wkv  = (const float*)d_in[4];
  const float* Wo   = (const float*)d_in[5];
  const float* W1   = (const float*)d_in[6];
  const float* W2   = (const float*)d_in[7];
  const float* W3   = (const float*)d_in[8];
  const float* cosb = (const float*)d_in[9];
  const float* sinb = (const float*)d_in[10];
  float* out = (float*)d_out;

  char* ws = (char*)d_ws;
  size_t off = 0;
  auto take = [&](size_t bytes) {
    size_t r = off;
    off += (bytes + 255) & ~(size_t)255;
    return r;
  };
  unsigned short* WqkvT = (unsigned short*)(ws + take((size_t)1536 * 1024 * 2));
  unsigned short* WoT   = (unsigned short*)(ws + take((size_t)1024 * 1024 * 2));
  unsigned short* W1T   = (unsigned short*)(ws + take((size_t)2688 * 1024 * 2));
  unsigned short* W3T   = (unsigned short*)(ws + take((size_t)2688 * 1024 * 2));
  unsigned short* W2T   = (unsigned short*)(ws + take((size_t)2688 * 1024 * 2));
  unsigned short* hA    = (unsigned short*)(ws + take((size_t)MM * DIM * 2));  // reused as h2
  unsigned short* gbuf  = (unsigned short*)(ws + take((size_t)MM * INTER * 2));
  unsigned short* qbuf = (unsigned short*)(ws + take((size_t)MM * DIM * 2));
  unsigned short* kbuf = (unsigned short*)(ws + take((size_t)BB * NKV * NN * HD * 2));
  unsigned short* vtb  = (unsigned short*)(ws + take((size_t)BB * NKV * NN * HD * 2));
  unsigned short* obuf = (unsigned short*)(ws + take((size_t)MM * DIM * 2));
  unsigned short* x2b  = (unsigned short*)(ws + take((size_t)MM * DIM * 2));

  transpose_all<<<10624, 256, 0, stream>>>(Wq, Wkv, Wo, W1, W3, W2,
                                           WqkvT, WoT, W1T, W3T, W2T);
  rmsnorm_k<float><<<MM, 256, 0, stream>>>(x, w_an, hA);
  gemm_qkv<<<dim3(1536 / 128, MM / 64), 256, 0, stream>>>(hA, WqkvT, cosb, sinb,
                                                          qbuf, kbuf, vtb);
  attn_k<<<dim3(NN / 128, NH, BB), 256, 0, stream>>>(qbuf, kbuf, vtb, obuf);
  // x2 (bf16) = x + o @ Wo
  gemm64<float, unsigned short><<<dim3(1024 / 128, MM / 64), 256, 0, stream>>>(
      obuf, WoT, x, x2b, 1024, 1024);
  rmsnorm_k<unsigned short><<<MM, 256, 0, stream>>>(x2b, w_fn, hA);
  gemm_ffn13<<<672, 512, 0, stream>>>(hA, W1T, W3T, gbuf, INTER, 1024);
  // out (fp32) = x2 + g @ W2
  gemm64<unsigned short, float><<<dim3(1024 / 128, MM / 64), 256, 0, stream>>>(
      gbuf, W2T, x2b, out, 1024, 2688);
}

// Round 13
// 225.087 us; speedup vs baseline: 1.0447x; 1.0447x over previous
//
#include <hip/hip_runtime.h>

#define DIM 1024
#define NH 16
#define NKV 4
#define HD 64
#define INTER 2688
#define BB 2
#define NN 2048
#define MM (BB*NN)

typedef __attribute__((ext_vector_type(4))) float f32x4;
typedef __attribute__((ext_vector_type(16))) float f32x16;
typedef __attribute__((ext_vector_type(8))) short short8;

#define CROW(r,h) ((((r)&3)) + 8*((r)>>2) + 4*(h))

__device__ __forceinline__ unsigned short f2bf(float f) {
  union { float f; unsigned u; } v; v.f = f;
  unsigned r = v.u + 0x7fffu + ((v.u >> 16) & 1u);
  return (unsigned short)(r >> 16);
}
__device__ __forceinline__ float bf2f(unsigned short u) {
  union { unsigned u; float f; } v; v.u = ((unsigned)u) << 16; return v.f;
}
__device__ __forceinline__ float ld_res(const float* p) { return *p; }
__device__ __forceinline__ float ld_res(const unsigned short* p) { return bf2f(*p); }
__device__ __forceinline__ void st_out(float* p, float v) { *p = v; }
__device__ __forceinline__ void st_out(unsigned short* p, float v) { *p = f2bf(v); }

// async global->LDS, 16B per lane; LDS dest = wave-uniform base + lane*16
__device__ __forceinline__ void glds16(const unsigned short* g, unsigned short* l) {
  __builtin_amdgcn_global_load_lds(
      (const __attribute__((address_space(1))) void*)g,
      (__attribute__((address_space(3))) void*)l, 16, 0, 0);
}

// XCD-aware block remap (requires gridDim.x*gridDim.y % 8 == 0; bijective).
__device__ __forceinline__ void xcd_map(int& bx, int& by) {
  int gx = gridDim.x;
  int nwg = gx * gridDim.y;
  int bid = (int)blockIdx.y * gx + (int)blockIdx.x;
  int cpx = nwg >> 3;
  int lg = (bid & 7) * cpx + (bid >> 3);
  bx = lg % gx;
  by = lg / gx;
}

// ---------------- merged weight transpose: fp32 [K][Nc] -> bf16 [Nc][K] -------------
__global__ void transpose_all(const float* __restrict__ Wq, const float* __restrict__ Wkv,
                              const float* __restrict__ Wo, const float* __restrict__ W1,
                              const float* __restrict__ W3, const float* __restrict__ W2,
                              unsigned short* __restrict__ WqkvT, unsigned short* __restrict__ WoT,
                              unsigned short* __restrict__ W1T, unsigned short* __restrict__ W3T,
                              unsigned short* __restrict__ W2T) {
  int tb = blockIdx.x;
  const float* src; unsigned short* dst; int K, Nc, t0;
  if (tb < 1024)        { src = Wq;  dst = WqkvT;                         K = 1024; Nc = 1024; t0 = tb; }
  else if (tb < 1536)   { src = Wkv; dst = WqkvT + (size_t)1024 * 1024;   K = 1024; Nc = 512;  t0 = tb - 1024; }
  else if (tb < 2560)   { src = Wo;  dst = WoT;                           K = 1024; Nc = 1024; t0 = tb - 1536; }
  else if (tb < 5248)   { src = W1;  dst = W1T;                           K = 1024; Nc = 2688; t0 = tb - 2560; }
  else if (tb < 7936)   { src = W3;  dst = W3T;                           K = 1024; Nc = 2688; t0 = tb - 5248; }
  else                  { src = W2;  dst = W2T;                           K = 2688; Nc = 1024; t0 = tb - 7936; }
  int ntx = Nc >> 5;
  int n0 = (t0 % ntx) * 32, k0 = (t0 / ntx) * 32;
  __shared__ float tile[32][33];
  int tx = threadIdx.x & 31, ty = threadIdx.x >> 5;
#pragma unroll
  for (int i = 0; i < 32; i += 8)
    tile[ty + i][tx] = src[(size_t)(k0 + ty + i) * Nc + n0 + tx];
  __syncthreads();
#pragma unroll
  for (int i = 0; i < 32; i += 8)
    dst[(size_t)(n0 + ty + i) * K + k0 + tx] = f2bf(tile[tx][ty + i]);
}

// ---------------- RMSNorm: [rows][1024] (fp32 or bf16 in) -> bf16 ----------------
template <typename InT>
__global__ void rmsnorm_k(const InT* __restrict__ x, const float* __restrict__ w,
                          unsigned short* __restrict__ h) {
  int row = blockIdx.x;
  int t = threadIdx.x;
  float4 v;
  if constexpr (sizeof(InT) == 4) {
    v = ((const float4*)(x + (size_t)row * DIM))[t];
  } else {
    ushort4 u = ((const ushort4*)(x + (size_t)row * DIM))[t];
    v.x = bf2f(u.x); v.y = bf2f(u.y); v.z = bf2f(u.z); v.w = bf2f(u.w);
  }
  float ss = v.x * v.x + v.y * v.y + v.z * v.z + v.w * v.w;
#pragma unroll
  for (int o = 1; o < 64; o <<= 1) ss += __shfl_xor(ss, o);
  __shared__ float ps[4];
  if ((t & 63) == 0) ps[t >> 6] = ss;
  __syncthreads();
  float r = rsqrtf((ps[0] + ps[1] + ps[2] + ps[3]) * (1.0f / DIM) + 1e-6f);
  float4 wv = ((const float4*)w)[t];
  ushort4 o4;
  o4.x = f2bf(v.x * r * wv.x);
  o4.y = f2bf(v.y * r * wv.y);
  o4.z = f2bf(v.z * r * wv.z);
  o4.w = f2bf(v.w * r * wv.w);
  *(ushort4*)(h + (size_t)row * DIM + t * 4) = o4;
}

// ---------------- GEMM64 v2: BM=64 x BN=128, BK=64, 2-phase glds dbuf ----------------
template <typename ResT, typename OutT>
__global__ __launch_bounds__(256, 3) void gemm64(
    const unsigned short* __restrict__ A, const unsigned short* __restrict__ Bt,
    const ResT* __restrict__ res, OutT* __restrict__ C, int Nc, int K) {
  __shared__ __align__(16) unsigned short Asm[2][64 * 64];
  __shared__ __align__(16) unsigned short Bsm[2][128 * 64];
  int tid = threadIdx.x;
  int w = tid >> 6, l = tid & 63;
  int bx, by;
  xcd_map(bx, by);
  int bm = by * 64, bn = bx * 128;
  int wc = w * 32;
  int c0 = l & 15, g = l >> 4;

  int sra = w * 16 + (l >> 3);
  int srb = w * 32 + (l >> 3);
  int schA = ((l & 7) ^ (l >> 3)) * 8;
  const unsigned short* gA = A + (size_t)(bm + sra) * K + schA;
  const unsigned short* gB = Bt + (size_t)(bn + srb) * K + schA;
  int lsa = (w * 16) * 64, lsb = (w * 32) * 64;

  f32x4 acc[4][2] = {};
  int T = K / 64;
  glds16(gA, &Asm[0][lsa]);
  glds16(gA + 8 * K, &Asm[0][lsa + 8 * 64]);
  glds16(gB, &Bsm[0][lsb]);
  glds16(gB + 8 * K, &Bsm[0][lsb + 8 * 64]);
  glds16(gB + 16 * K, &Bsm[0][lsb + 16 * 64]);
  glds16(gB + 24 * K, &Bsm[0][lsb + 24 * 64]);
  __syncthreads();
  int buf = 0;
  for (int s = 0; s < T; ++s) {
    int nb = buf ^ 1;
    if (s + 1 < T) {
      int ko = (s + 1) * 64;
      glds16(gA + ko, &Asm[nb][lsa]);
      glds16(gA + 8 * K + ko, &Asm[nb][lsa + 8 * 64]);
      glds16(gB + ko, &Bsm[nb][lsb]);
      glds16(gB + 8 * K + ko, &Bsm[nb][lsb + 8 * 64]);
      glds16(gB + 16 * K + ko, &Bsm[nb][lsb + 16 * 64]);
      glds16(gB + 24 * K + ko, &Bsm[nb][lsb + 24 * 64]);
    }
    const unsigned short* As = Asm[buf];
    const unsigned short* Bs = Bsm[buf];
#pragma unroll
    for (int ks = 0; ks < 2; ++ks) {
      short8 af[4], bf[2];
#pragma unroll
      for (int m = 0; m < 4; m++) {
        int ra = m * 16 + c0;
        af[m] = *(const short8*)&As[ra * 64 + (((ks * 4 + g) ^ (ra & 7)) * 8)];
      }
#pragma unroll
      for (int n = 0; n < 2; n++) {
        int rb = wc + n * 16 + c0;
        bf[n] = *(const short8*)&Bs[rb * 64 + (((ks * 4 + g) ^ (rb & 7)) * 8)];
      }
      __builtin_amdgcn_s_setprio(1);
#pragma unroll
      for (int m = 0; m < 4; m++)
#pragma unroll
        for (int n = 0; n < 2; n++)
          acc[m][n] = __builtin_amdgcn_mfma_f32_16x16x32_bf16(af[m], bf[n], acc[m][n], 0, 0, 0);
      __builtin_amdgcn_s_setprio(0);
    }
    __syncthreads();
    buf = nb;
  }
  int gq = l >> 4;
#pragma unroll
  for (int m = 0; m < 4; m++) {
#pragma unroll
    for (int i = 0; i < 4; i++) {
      int row = bm + m * 16 + gq * 4 + i;
#pragma unroll
      for (int n = 0; n < 2; n++) {
        int col = bn + wc + n * 16 + c0;
        float v = acc[m][n][i] + ld_res(&res[(size_t)row * Nc + col]);
        st_out(&C[(size_t)row * Nc + col], v);
      }
    }
  }
}

// ---------------- QKV GEMM (BK=64) with fused RoPE epilogue ----------------
__global__ __launch_bounds__(256, 3) void gemm_qkv(
    const unsigned short* __restrict__ A, const unsigned short* __restrict__ Bt,
    const float* __restrict__ cosb, const float* __restrict__ sinb,
    unsigned short* __restrict__ qb, unsigned short* __restrict__ kb,
    unsigned short* __restrict__ vtb) {
  const int K = 1024;
  const float QS = 0.125f * 1.44269504f;
  __shared__ __align__(16) unsigned short Asm[2][64 * 64];
  __shared__ __align__(16) unsigned short Bsm[2][128 * 64];
  int tid = threadIdx.x;
  int w = tid >> 6, l = tid & 63;
  int bx, by;
  xcd_map(bx, by);
  int bm = by * 64, bn = bx * 128;
  int wc = w * 32;
  int c0 = l & 15, g = l >> 4;

  int sra = w * 16 + (l >> 3);
  int srb = w * 32 + (l >> 3);
  int schA = ((l & 7) ^ (l >> 3)) * 8;
  const unsigned short* gA = A + (size_t)(bm + sra) * K + schA;
  const unsigned short* gB = Bt + (size_t)(bn + srb) * K + schA;
  int lsa = (w * 16) * 64, lsb = (w * 32) * 64;

  f32x4 acc[4][2] = {};
  int T = K / 64;
  glds16(gA, &Asm[0][lsa]);
  glds16(gA + 8 * K, &Asm[0][lsa + 8 * 64]);
  glds16(gB, &Bsm[0][lsb]);
  glds16(gB + 8 * K, &Bsm[0][lsb + 8 * 64]);
  glds16(gB + 16 * K, &Bsm[0][lsb + 16 * 64]);
  glds16(gB + 24 * K, &Bsm[0][lsb + 24 * 64]);
  __syncthreads();
  int buf = 0;
  for (int s = 0; s < T; ++s) {
    int nb = buf ^ 1;
    if (s + 1 < T) {
      int ko = (s + 1) * 64;
      glds16(gA + ko, &Asm[nb][lsa]);
      glds16(gA + 8 * K + ko, &Asm[nb][lsa + 8 * 64]);
      glds16(gB + ko, &Bsm[nb][lsb]);
      glds16(gB + 8 * K + ko, &Bsm[nb][lsb + 8 * 64]);
      glds16(gB + 16 * K + ko, &Bsm[nb][lsb + 16 * 64]);
      glds16(gB + 24 * K + ko, &Bsm[nb][lsb + 24 * 64]);
    }
    const unsigned short* As = Asm[buf];
    const unsigned short* Bs = Bsm[buf];
#pragma unroll
    for (int ks = 0; ks < 2; ++ks) {
      short8 af[4], bf[2];
#pragma unroll
      for (int m = 0; m < 4; m++) {
        int ra = m * 16 + c0;
        af[m] = *(const short8*)&As[ra * 64 + (((ks * 4 + g) ^ (ra & 7)) * 8)];
      }
#pragma unroll
      for (int n = 0; n < 2; n++) {
        int rb = wc + n * 16 + c0;
        bf[n] = *(const short8*)&Bs[rb * 64 + (((ks * 4 + g) ^ (rb & 7)) * 8)];
      }
      __builtin_amdgcn_s_setprio(1);
#pragma unroll
      for (int m = 0; m < 4; m++)
#pragma unroll
        for (int n = 0; n < 2; n++)
          acc[m][n] = __builtin_amdgcn_mfma_f32_16x16x32_bf16(af[m], bf[n], acc[m][n], 0, 0, 0);
      __builtin_amdgcn_s_setprio(0);
    }
    __syncthreads();
    buf = nb;
  }
  int gq = l >> 4;
  int lodd = c0 & 1;
#pragma unroll
  for (int m = 0; m < 4; m++) {
#pragma unroll
    for (int i = 0; i < 4; i++) {
      int row = bm + m * 16 + gq * 4 + i;
      int b = row >> 11, tok = row & (NN - 1);
#pragma unroll
      for (int n = 0; n < 2; n++) {
        int col = bn + wc + n * 16 + c0;
        float val = acc[m][n][i];
        float partner = __shfl_xor(val, 1);
        if (bn < 1024) {
          int head = col >> 6, d = col & 63, j = d >> 1;
          float c = cosb[tok * 32 + j], s = sinb[tok * 32 + j];
          float r = lodd ? (partner * s + val * c) : (val * c - partner * s);
          qb[(((size_t)(b * NH + head)) * NN + tok) * 64 + d] = f2bf(r * QS);
        } else if (bn < 1280) {
          int cc = col - 1024;
          int kvh = cc >> 6, d = cc & 63, j = d >> 1;
          float c = cosb[tok * 32 + j], s = sinb[tok * 32 + j];
          float r = lodd ? (partner * s + val * c) : (val * c - partner * s);
          kb[(((size_t)(b * NKV + kvh)) * NN + tok) * 64 + d] = f2bf(r);
        } else {
          int cc = col - 1280;
          int kvh = cc >> 6, d = cc & 63;
          vtb[(((size_t)(b * NKV + kvh)) * 64 + d) * NN + tok] = f2bf(val);
        }
      }
    }
  }
}

// ---------------- fused FFN13 v7: 8-wave BM=128 x BN=128-of-each, BK=32 --------------
// r4 champion per-wave ratio (16 MFMA / 8 ds_read) at 2x wave count:
// wave (wm,wn) in 2x4 grid -> 64x32 of BOTH a1,a3 (acc=64 VGPR). 3 glds/wave/step.
// LDS 48 KB, 2-phase dbuf, (512,4) -> 2 blocks/CU = 16 waves/CU.
__global__ __launch_bounds__(512, 4) void gemm_ffn13(
    const unsigned short* __restrict__ A, const unsigned short* __restrict__ B1t,
    const unsigned short* __restrict__ B3t, unsigned short* __restrict__ G,
    int Nc, int K) {
  __shared__ __align__(16) unsigned short Asm[2][128 * 32];
  __shared__ __align__(16) unsigned short B1sm[2][128 * 32];
  __shared__ __align__(16) unsigned short B3sm[2][128 * 32];
  int tid = threadIdx.x;
  int w = tid >> 6, l = tid & 63;
  int bm = blockIdx.y * 128, bn = blockIdx.x * 128;
  int wm = w >> 2, wn = w & 3;
  int c0 = l & 15, g = l >> 4;

  // staging: wave w stages rows [w*16, w*16+16) of A, B1, B3 (1 glds call each)
  int sr = w * 16 + (l >> 2);
  int sc = ((l & 3) ^ ((sr >> 1) & 3)) * 8;
  const unsigned short* gA  = A   + (size_t)(bm + sr) * K + sc;
  const unsigned short* gB1 = B1t + (size_t)(bn + sr) * K + sc;
  const unsigned short* gB3 = B3t + (size_t)(bn + sr) * K + sc;
  int ls = (w * 16) * 32;

  int aoff[4], boff[2];
#pragma unroll
  for (int m = 0; m < 4; m++) {
    int ra = wm * 64 + m * 16 + c0;
    aoff[m] = ra * 32 + (g ^ ((ra >> 1) & 3)) * 8;
  }
#pragma unroll
  for (int n = 0; n < 2; n++) {
    int rb = wn * 32 + n * 16 + c0;
    boff[n] = rb * 32 + (g ^ ((rb >> 1) & 3)) * 8;
  }

  f32x4 a1[4][2] = {};
  f32x4 a3[4][2] = {};
  int nsteps = K / 32;
  glds16(gA, &Asm[0][ls]);
  glds16(gB1, &B1sm[0][ls]);
  glds16(gB3, &B3sm[0][ls]);
  __syncthreads();
  int buf = 0;
  for (int s = 0; s < nsteps; ++s) {
    int nb = buf ^ 1;
    if (s + 1 < nsteps) {
      int ko = (s + 1) * 32;
      glds16(gA + ko, &Asm[nb][ls]);
      glds16(gB1 + ko, &B1sm[nb][ls]);
      glds16(gB3 + ko, &B3sm[nb][ls]);
    }
    const unsigned short* As = Asm[buf];
    const unsigned short* B1s = B1sm[buf];
    const unsigned short* B3s = B3sm[buf];
    short8 af[4], b1f[2], b3f[2];
#pragma unroll
    for (int m = 0; m < 4; m++) af[m] = *(const short8*)&As[aoff[m]];
#pragma unroll
    for (int n = 0; n < 2; n++) {
      b1f[n] = *(const short8*)&B1s[boff[n]];
      b3f[n] = *(const short8*)&B3s[boff[n]];
    }
    __builtin_amdgcn_s_setprio(1);
#pragma unroll
    for (int m = 0; m < 4; m++)
#pragma unroll
      for (int n = 0; n < 2; n++) {
        a1[m][n] = __builtin_amdgcn_mfma_f32_16x16x32_bf16(af[m], b1f[n], a1[m][n], 0, 0, 0);
        a3[m][n] = __builtin_amdgcn_mfma_f32_16x16x32_bf16(af[m], b3f[n], a3[m][n], 0, 0, 0);
      }
    __builtin_amdgcn_s_setprio(0);
    __syncthreads();
    buf = nb;
  }
  int gq = l >> 4;
#pragma unroll
  for (int m = 0; m < 4; m++) {
#pragma unroll
    for (int i = 0; i < 4; i++) {
      int row = bm + wm * 64 + m * 16 + gq * 4 + i;
#pragma unroll
      for (int n = 0; n < 2; n++) {
        int col = bn + wn * 32 + n * 16 + c0;
        float x1 = a1[m][n][i], x3 = a3[m][n][i];
        float sg = x1 / (1.0f + __expf(-x1));
        G[(size_t)row * Nc + col] = f2bf(sg * x3);
      }
    }
  }
}

// ---------------- flash attention v5: exp2 domain + defer-max (T13) ----------------
__global__ __launch_bounds__(256, 3) void attn_k(
    const unsigned short* __restrict__ qg_, const unsigned short* __restrict__ kg_,
    const unsigned short* __restrict__ vg_, unsigned short* __restrict__ ob) {
  __shared__ __align__(16) unsigned short Ksm[2][64 * 64];
  __shared__ __align__(16) unsigned short Vsm[2][64 * 64];
  int qb = (blockIdx.z == 0) ? (int)blockIdx.x : ((int)gridDim.x - 1 - (int)blockIdx.x);
  int h = blockIdx.y, b = blockIdx.z;
  int kvh = h & 3;  // jnp.tile semantics
  int tid = threadIdx.x, w = tid >> 6, l = tid & 63;
  int q5 = l & 31, hi = l >> 5;
  int qwbase = qb * 128 + w * 32;
  int qgl = qwbase + q5;

  const unsigned short* Kg = kg_ + ((size_t)(b * NKV + kvh)) * NN * 64;
  const unsigned short* Vg = vg_ + ((size_t)(b * NKV + kvh)) * 64 * NN;

  short8 qf[4];
  {
    const unsigned short* qrow = qg_ + (((size_t)(b * NH + h)) * NN + qgl) * 64 + hi * 8;
#pragma unroll
    for (int d = 0; d < 4; d++) qf[d] = *(const short8*)(qrow + d * 16);
  }

  int srow = l >> 3;
  int schunk = (l & 7) ^ (srow & 7);
  const unsigned short* gK = Kg + (size_t)(w * 16 + srow) * 64 + schunk * 8;
  const unsigned short* gV = Vg + (size_t)(w * 16 + srow) * NN + schunk * 8;

  int nkt = qb * 2 + 2;
  int nkt_w = ((qwbase + 31) >> 6) + 1;

  f32x16 O0 = {}, O1 = {};
  float m_r = -1e30f, l_r = 0.0f;

  glds16(gK, &Ksm[0][w * 1024]);
  glds16(gK + 8 * 64, &Ksm[0][w * 1024 + 512]);
  glds16(gV, &Vsm[0][w * 1024]);
  glds16(gV + 8 * NN, &Vsm[0][w * 1024 + 512]);
  __syncthreads();

  int buf = 0;
  for (int kt = 0; kt < nkt; ++kt) {
    int n0 = kt * 64;
    if (kt + 1 < nkt) {
      int nb = buf ^ 1;
      glds16(gK + (size_t)(n0 + 64) * 64, &Ksm[nb][w * 1024]);
      glds16(gK + (size_t)(n0 + 64) * 64 + 8 * 64, &Ksm[nb][w * 1024 + 512]);
      glds16(gV + n0 + 64, &Vsm[nb][w * 1024]);
      glds16(gV + 8 * NN + n0 + 64, &Vsm[nb][w * 1024 + 512]);
    }
    if (kt < nkt_w) {
      const unsigned short* Ks = Ksm[buf];
      const unsigned short* Vs = Vsm[buf];
      f32x16 S[2];
      __builtin_amdgcn_s_setprio(1);
#pragma unroll
      for (int s = 0; s < 2; s++) {
        f32x16 acc = {};
        int row = s * 32 + q5;
#pragma unroll
        for (int d = 0; d < 4; d++) {
          int ch = (2 * d + hi) ^ (row & 7);
          short8 kf = *(const short8*)&Ks[row * 64 + ch * 8];
          acc = __builtin_amdgcn_mfma_f32_32x32x16_bf16(kf, qf[d], acc, 0, 0, 0);
        }
        S[s] = acc;
      }
      __builtin_amdgcn_s_setprio(0);
      if (kt == nkt_w - 1) {
#pragma unroll
        for (int s = 0; s < 2; s++)
#pragma unroll
          for (int r = 0; r < 16; r++) {
            int kg = n0 + s * 32 + CROW(r, hi);
            S[s][r] = (kg > qgl) ? -1e30f : S[s][r];
          }
      }
      float t16[16];
#pragma unroll
      for (int r = 0; r < 16; r++) t16[r] = fmaxf(S[0][r], S[1][r]);
#pragma unroll
      for (int k = 8; k >= 1; k >>= 1)
#pragma unroll
        for (int r = 0; r < k; r++) t16[r] = fmaxf(t16[r], t16[r + k]);
      float pm = fmaxf(t16[0], __shfl_xor(t16[0], 32));
      if (!__all(pm <= m_r + 8.0f)) {
        float mn = fmaxf(m_r, pm);
        float alpha = exp2f(m_r - mn);
        m_r = mn;
        l_r *= alpha;
        float ab[16];
#pragma unroll
        for (int r = 0; r < 16; r++) ab[r] = __shfl(alpha, CROW(r, 0) + 4 * hi);
#pragma unroll
        for (int r = 0; r < 16; r++) { O0[r] *= ab[r]; O1[r] *= ab[r]; }
      }
#pragma unroll
      for (int s = 0; s < 2; s++)
#pragma unroll
        for (int r = 0; r < 16; r++) S[s][r] = exp2f(S[s][r] - m_r);
      float u[16];
#pragma unroll
      for (int r = 0; r < 16; r++) u[r] = S[0][r] + S[1][r];
#pragma unroll
      for (int k = 8; k >= 1; k >>= 1)
#pragma unroll
        for (int r = 0; r < k; r++) u[r] += u[r + k];
      l_r += (u[0] + __shfl_xor(u[0], 32));
      short8 paf[4];
#pragma unroll
      for (int ks = 0; ks < 4; ks++) {
        const int s = ks >> 1, e = ks & 1;
        unsigned a0, a1, b0, b1;
        asm("v_cvt_pk_bf16_f32 %0, %1, %2" : "=v"(a0) : "v"(S[s][8*e+0]), "v"(S[s][8*e+1]));
        asm("v_cvt_pk_bf16_f32 %0, %1, %2" : "=v"(a1) : "v"(S[s][8*e+2]), "v"(S[s][8*e+3]));
        asm("v_cvt_pk_bf16_f32 %0, %1, %2" : "=v"(b0) : "v"(S[s][8*e+4]), "v"(S[s][8*e+5]));
        asm("v_cvt_pk_bf16_f32 %0, %1, %2" : "=v"(b1) : "v"(S[s][8*e+6]), "v"(S[s][8*e+7]));
        asm("v_permlane32_swap_b32 %0, %1" : "+v"(a0), "+v"(b0));
        asm("v_permlane32_swap_b32 %0, %1" : "+v"(a1), "+v"(b1));
        union { unsigned u4[4]; short8 s8; } pk;
        pk.u4[0] = a0; pk.u4[1] = a1; pk.u4[2] = b0; pk.u4[3] = b1;
        paf[ks] = pk.s8;
      }
      __builtin_amdgcn_s_setprio(1);
#pragma unroll
      for (int ks = 0; ks < 4; ks++) {
        int row0 = q5, row1 = 32 + q5;
        short8 vf0 = *(const short8*)&Vs[row0 * 64 + (((2 * ks + hi) ^ (row0 & 7)) * 8)];
        short8 vf1 = *(const short8*)&Vs[row1 * 64 + (((2 * ks + hi) ^ (row1 & 7)) * 8)];
        O0 = __builtin_amdgcn_mfma_f32_32x32x16_bf16(paf[ks], vf0, O0, 0, 0, 0);
        O1 = __builtin_amdgcn_mfma_f32_32x32x16_bf16(paf[ks], vf1, O1, 0, 0, 0);
      }
      __builtin_amdgcn_s_setprio(0);
    }
    __syncthreads();
    buf ^= 1;
  }
  float linv = 1.0f / l_r;
  float lb[16];
#pragma unroll
  for (int r = 0; r < 16; r++) lb[r] = __shfl(linv, CROW(r, 0) + 4 * hi);
#pragma unroll
  for (int r = 0; r < 16; r++) {
    int orow = qwbase + CROW(r, hi);
    size_t base = ((size_t)b * NN + orow) * 1024 + h * 64 + q5;
    ob[base] = f2bf(O0[r] * lb[r]);
    ob[base + 32] = f2bf(O1[r] * lb[r]);
  }
}

// ---------------- launcher ----------------
extern "C" void kernel_launch(void* const* d_in, const int* in_sizes, int n_in,
                              void* d_out, int out_size, void* d_ws, size_t ws_size,
                              hipStream_t stream) {
  (void)in_sizes; (void)n_in; (void)out_size; (void)ws_size;
  const float* x    = (const float*)d_in[0];
  const float* w_an = (const float*)d_in[1];
  const float* w_fn = (const float*)d_in[2];
  const float* Wq   = (const float*)d_in[3];
  const float* Wkv  = (const float*)d_in[4];
  const float* Wo   = (const float*)d_in[5];
  const float* W1   = (const float*)d_in[6];
  const float* W2   = (const float*)d_in[7];
  const float* W3   = (const float*)d_in[8];
  const float* cosb = (const float*)d_in[9];
  const float* sinb = (const float*)d_in[10];
  float* out = (float*)d_out;

  char* ws = (char*)d_ws;
  size_t off = 0;
  auto take = [&](size_t bytes) {
    size_t r = off;
    off += (bytes + 255) & ~(size_t)255;
    return r;
  };
  unsigned short* WqkvT = (unsigned short*)(ws + take((size_t)1536 * 1024 * 2));
  unsigned short* WoT   = (unsigned short*)(ws + take((size_t)1024 * 1024 * 2));
  unsigned short* W1T   = (unsigned short*)(ws + take((size_t)2688 * 1024 * 2));
  unsigned short* W3T   = (unsigned short*)(ws + take((size_t)2688 * 1024 * 2));
  unsigned short* W2T   = (unsigned short*)(ws + take((size_t)2688 * 1024 * 2));
  unsigned short* hA    = (unsigned short*)(ws + take((size_t)MM * DIM * 2));  // reused as h2
  unsigned short* gbuf  = (unsigned short*)(ws + take((size_t)MM * INTER * 2));
  unsigned short* qbuf = (unsigned short*)(ws + take((size_t)MM * DIM * 2));
  unsigned short* kbuf = (unsigned short*)(ws + take((size_t)BB * NKV * NN * HD * 2));
  unsigned short* vtb  = (unsigned short*)(ws + take((size_t)BB * NKV * NN * HD * 2));
  unsigned short* obuf = (unsigned short*)(ws + take((size_t)MM * DIM * 2));
  unsigned short* x2b  = (unsigned short*)(ws + take((size_t)MM * DIM * 2));

  transpose_all<<<10624, 256, 0, stream>>>(Wq, Wkv, Wo, W1, W3, W2,
                                           WqkvT, WoT, W1T, W3T, W2T);
  rmsnorm_k<float><<<MM, 256, 0, stream>>>(x, w_an, hA);
  gemm_qkv<<<dim3(1536 / 128, MM / 64), 256, 0, stream>>>(hA, WqkvT, cosb, sinb,
                                                          qbuf, kbuf, vtb);
  attn_k<<<dim3(NN / 128, NH, BB), 256, 0, stream>>>(qbuf, kbuf, vtb, obuf);
  // x2 (bf16) = x + o @ Wo
  gemm64<float, unsigned short><<<dim3(1024 / 128, MM / 64), 256, 0, stream>>>(
      obuf, WoT, x, x2b, 1024, 1024);
  rmsnorm_k<unsigned short><<<MM, 256, 0, stream>>>(x2b, w_fn, hA);
  gemm_ffn13<<<dim3(INTER / 128, MM / 128), 512, 0, stream>>>(hA, W1T, W3T, gbuf, INTER, 1024);
  // out (fp32) = x2 + g @ W2
  gemm64<unsigned short, float><<<dim3(1024 / 128, MM / 64), 256, 0, stream>>>(
      gbuf, W2T, x2b, out, 1024, 2688);
}

// Round 14
// 215.692 us; speedup vs baseline: 1.0902x; 1.0436x over previous
//
#include <hip/hip_runtime.h>

#define DIM 1024
#define NH 16
#define NKV 4
#define HD 64
#define INTER 2688
#define BB 2
#define NN 2048
#define MM (BB*NN)

typedef __attribute__((ext_vector_type(4))) float f32x4;
typedef __attribute__((ext_vector_type(16))) float f32x16;
typedef __attribute__((ext_vector_type(8))) short short8;

#define CROW(r,h) ((((r)&3)) + 8*((r)>>2) + 4*(h))

__device__ __forceinline__ unsigned short f2bf(float f) {
  union { float f; unsigned u; } v; v.f = f;
  unsigned r = v.u + 0x7fffu + ((v.u >> 16) & 1u);
  return (unsigned short)(r >> 16);
}
__device__ __forceinline__ float bf2f(unsigned short u) {
  union { unsigned u; float f; } v; v.u = ((unsigned)u) << 16; return v.f;
}
__device__ __forceinline__ float ld_res(const float* p) { return *p; }
__device__ __forceinline__ float ld_res(const unsigned short* p) { return bf2f(*p); }
__device__ __forceinline__ void st_out(float* p, float v) { *p = v; }
__device__ __forceinline__ void st_out(unsigned short* p, float v) { *p = f2bf(v); }

// async global->LDS, 16B per lane; LDS dest = wave-uniform base + lane*16
__device__ __forceinline__ void glds16(const unsigned short* g, unsigned short* l) {
  __builtin_amdgcn_global_load_lds(
      (const __attribute__((address_space(1))) void*)g,
      (__attribute__((address_space(3))) void*)l, 16, 0, 0);
}

// XCD-aware block remap (requires gridDim.x*gridDim.y % 8 == 0; bijective).
__device__ __forceinline__ void xcd_map(int& bx, int& by) {
  int gx = gridDim.x;
  int nwg = gx * gridDim.y;
  int bid = (int)blockIdx.y * gx + (int)blockIdx.x;
  int cpx = nwg >> 3;
  int lg = (bid & 7) * cpx + (bid >> 3);
  bx = lg % gx;
  by = lg / gx;
}

// ---------------- merged weight transpose: fp32 [K][Nc] -> bf16 [Nc][K] -------------
__global__ void transpose_all(const float* __restrict__ Wq, const float* __restrict__ Wkv,
                              const float* __restrict__ Wo, const float* __restrict__ W1,
                              const float* __restrict__ W3, const float* __restrict__ W2,
                              unsigned short* __restrict__ WqkvT, unsigned short* __restrict__ WoT,
                              unsigned short* __restrict__ W1T, unsigned short* __restrict__ W3T,
                              unsigned short* __restrict__ W2T) {
  int tb = blockIdx.x;
  const float* src; unsigned short* dst; int K, Nc, t0;
  if (tb < 1024)        { src = Wq;  dst = WqkvT;                         K = 1024; Nc = 1024; t0 = tb; }
  else if (tb < 1536)   { src = Wkv; dst = WqkvT + (size_t)1024 * 1024;   K = 1024; Nc = 512;  t0 = tb - 1024; }
  else if (tb < 2560)   { src = Wo;  dst = WoT;                           K = 1024; Nc = 1024; t0 = tb - 1536; }
  else if (tb < 5248)   { src = W1;  dst = W1T;                           K = 1024; Nc = 2688; t0 = tb - 2560; }
  else if (tb < 7936)   { src = W3;  dst = W3T;                           K = 1024; Nc = 2688; t0 = tb - 5248; }
  else                  { src = W2;  dst = W2T;                           K = 2688; Nc = 1024; t0 = tb - 7936; }
  int ntx = Nc >> 5;
  int n0 = (t0 % ntx) * 32, k0 = (t0 / ntx) * 32;
  __shared__ float tile[32][33];
  int tx = threadIdx.x & 31, ty = threadIdx.x >> 5;
#pragma unroll
  for (int i = 0; i < 32; i += 8)
    tile[ty + i][tx] = src[(size_t)(k0 + ty + i) * Nc + n0 + tx];
  __syncthreads();
#pragma unroll
  for (int i = 0; i < 32; i += 8)
    dst[(size_t)(n0 + ty + i) * K + k0 + tx] = f2bf(tile[tx][ty + i]);
}

// ---------------- RMSNorm: [rows][1024] (fp32 or bf16 in) -> bf16 ----------------
template <typename InT>
__global__ void rmsnorm_k(const InT* __restrict__ x, const float* __restrict__ w,
                          unsigned short* __restrict__ h) {
  int row = blockIdx.x;
  int t = threadIdx.x;
  float4 v;
  if constexpr (sizeof(InT) == 4) {
    v = ((const float4*)(x + (size_t)row * DIM))[t];
  } else {
    ushort4 u = ((const ushort4*)(x + (size_t)row * DIM))[t];
    v.x = bf2f(u.x); v.y = bf2f(u.y); v.z = bf2f(u.z); v.w = bf2f(u.w);
  }
  float ss = v.x * v.x + v.y * v.y + v.z * v.z + v.w * v.w;
#pragma unroll
  for (int o = 1; o < 64; o <<= 1) ss += __shfl_xor(ss, o);
  __shared__ float ps[4];
  if ((t & 63) == 0) ps[t >> 6] = ss;
  __syncthreads();
  float r = rsqrtf((ps[0] + ps[1] + ps[2] + ps[3]) * (1.0f / DIM) + 1e-6f);
  float4 wv = ((const float4*)w)[t];
  ushort4 o4;
  o4.x = f2bf(v.x * r * wv.x);
  o4.y = f2bf(v.y * r * wv.y);
  o4.z = f2bf(v.z * r * wv.z);
  o4.w = f2bf(v.w * r * wv.w);
  *(ushort4*)(h + (size_t)row * DIM + t * 4) = o4;
}

// ---------------- GEMM64 v2: BM=64 x BN=128, BK=64, 2-phase glds dbuf ----------------
template <typename ResT, typename OutT>
__global__ __launch_bounds__(256, 3) void gemm64(
    const unsigned short* __restrict__ A, const unsigned short* __restrict__ Bt,
    const ResT* __restrict__ res, OutT* __restrict__ C, int Nc, int K) {
  __shared__ __align__(16) unsigned short Asm[2][64 * 64];
  __shared__ __align__(16) unsigned short Bsm[2][128 * 64];
  int tid = threadIdx.x;
  int w = tid >> 6, l = tid & 63;
  int bx, by;
  xcd_map(bx, by);
  int bm = by * 64, bn = bx * 128;
  int wc = w * 32;
  int c0 = l & 15, g = l >> 4;

  int sra = w * 16 + (l >> 3);
  int srb = w * 32 + (l >> 3);
  int schA = ((l & 7) ^ (l >> 3)) * 8;
  const unsigned short* gA = A + (size_t)(bm + sra) * K + schA;
  const unsigned short* gB = Bt + (size_t)(bn + srb) * K + schA;
  int lsa = (w * 16) * 64, lsb = (w * 32) * 64;

  f32x4 acc[4][2] = {};
  int T = K / 64;
  glds16(gA, &Asm[0][lsa]);
  glds16(gA + 8 * K, &Asm[0][lsa + 8 * 64]);
  glds16(gB, &Bsm[0][lsb]);
  glds16(gB + 8 * K, &Bsm[0][lsb + 8 * 64]);
  glds16(gB + 16 * K, &Bsm[0][lsb + 16 * 64]);
  glds16(gB + 24 * K, &Bsm[0][lsb + 24 * 64]);
  __syncthreads();
  int buf = 0;
  for (int s = 0; s < T; ++s) {
    int nb = buf ^ 1;
    if (s + 1 < T) {
      int ko = (s + 1) * 64;
      glds16(gA + ko, &Asm[nb][lsa]);
      glds16(gA + 8 * K + ko, &Asm[nb][lsa + 8 * 64]);
      glds16(gB + ko, &Bsm[nb][lsb]);
      glds16(gB + 8 * K + ko, &Bsm[nb][lsb + 8 * 64]);
      glds16(gB + 16 * K + ko, &Bsm[nb][lsb + 16 * 64]);
      glds16(gB + 24 * K + ko, &Bsm[nb][lsb + 24 * 64]);
    }
    const unsigned short* As = Asm[buf];
    const unsigned short* Bs = Bsm[buf];
#pragma unroll
    for (int ks = 0; ks < 2; ++ks) {
      short8 af[4], bf[2];
#pragma unroll
      for (int m = 0; m < 4; m++) {
        int ra = m * 16 + c0;
        af[m] = *(const short8*)&As[ra * 64 + (((ks * 4 + g) ^ (ra & 7)) * 8)];
      }
#pragma unroll
      for (int n = 0; n < 2; n++) {
        int rb = wc + n * 16 + c0;
        bf[n] = *(const short8*)&Bs[rb * 64 + (((ks * 4 + g) ^ (rb & 7)) * 8)];
      }
      __builtin_amdgcn_s_setprio(1);
#pragma unroll
      for (int m = 0; m < 4; m++)
#pragma unroll
        for (int n = 0; n < 2; n++)
          acc[m][n] = __builtin_amdgcn_mfma_f32_16x16x32_bf16(af[m], bf[n], acc[m][n], 0, 0, 0);
      __builtin_amdgcn_s_setprio(0);
    }
    __syncthreads();
    buf = nb;
  }
  int gq = l >> 4;
#pragma unroll
  for (int m = 0; m < 4; m++) {
#pragma unroll
    for (int i = 0; i < 4; i++) {
      int row = bm + m * 16 + gq * 4 + i;
#pragma unroll
      for (int n = 0; n < 2; n++) {
        int col = bn + wc + n * 16 + c0;
        float v = acc[m][n][i] + ld_res(&res[(size_t)row * Nc + col]);
        st_out(&C[(size_t)row * Nc + col], v);
      }
    }
  }
}

// ---------------- QKV GEMM (BK=64) with fused RoPE epilogue ----------------
__global__ __launch_bounds__(256, 3) void gemm_qkv(
    const unsigned short* __restrict__ A, const unsigned short* __restrict__ Bt,
    const float* __restrict__ cosb, const float* __restrict__ sinb,
    unsigned short* __restrict__ qb, unsigned short* __restrict__ kb,
    unsigned short* __restrict__ vtb) {
  const int K = 1024;
  const float QS = 0.125f * 1.44269504f;
  __shared__ __align__(16) unsigned short Asm[2][64 * 64];
  __shared__ __align__(16) unsigned short Bsm[2][128 * 64];
  int tid = threadIdx.x;
  int w = tid >> 6, l = tid & 63;
  int bx, by;
  xcd_map(bx, by);
  int bm = by * 64, bn = bx * 128;
  int wc = w * 32;
  int c0 = l & 15, g = l >> 4;

  int sra = w * 16 + (l >> 3);
  int srb = w * 32 + (l >> 3);
  int schA = ((l & 7) ^ (l >> 3)) * 8;
  const unsigned short* gA = A + (size_t)(bm + sra) * K + schA;
  const unsigned short* gB = Bt + (size_t)(bn + srb) * K + schA;
  int lsa = (w * 16) * 64, lsb = (w * 32) * 64;

  f32x4 acc[4][2] = {};
  int T = K / 64;
  glds16(gA, &Asm[0][lsa]);
  glds16(gA + 8 * K, &Asm[0][lsa + 8 * 64]);
  glds16(gB, &Bsm[0][lsb]);
  glds16(gB + 8 * K, &Bsm[0][lsb + 8 * 64]);
  glds16(gB + 16 * K, &Bsm[0][lsb + 16 * 64]);
  glds16(gB + 24 * K, &Bsm[0][lsb + 24 * 64]);
  __syncthreads();
  int buf = 0;
  for (int s = 0; s < T; ++s) {
    int nb = buf ^ 1;
    if (s + 1 < T) {
      int ko = (s + 1) * 64;
      glds16(gA + ko, &Asm[nb][lsa]);
      glds16(gA + 8 * K + ko, &Asm[nb][lsa + 8 * 64]);
      glds16(gB + ko, &Bsm[nb][lsb]);
      glds16(gB + 8 * K + ko, &Bsm[nb][lsb + 8 * 64]);
      glds16(gB + 16 * K + ko, &Bsm[nb][lsb + 16 * 64]);
      glds16(gB + 24 * K + ko, &Bsm[nb][lsb + 24 * 64]);
    }
    const unsigned short* As = Asm[buf];
    const unsigned short* Bs = Bsm[buf];
#pragma unroll
    for (int ks = 0; ks < 2; ++ks) {
      short8 af[4], bf[2];
#pragma unroll
      for (int m = 0; m < 4; m++) {
        int ra = m * 16 + c0;
        af[m] = *(const short8*)&As[ra * 64 + (((ks * 4 + g) ^ (ra & 7)) * 8)];
      }
#pragma unroll
      for (int n = 0; n < 2; n++) {
        int rb = wc + n * 16 + c0;
        bf[n] = *(const short8*)&Bs[rb * 64 + (((ks * 4 + g) ^ (rb & 7)) * 8)];
      }
      __builtin_amdgcn_s_setprio(1);
#pragma unroll
      for (int m = 0; m < 4; m++)
#pragma unroll
        for (int n = 0; n < 2; n++)
          acc[m][n] = __builtin_amdgcn_mfma_f32_16x16x32_bf16(af[m], bf[n], acc[m][n], 0, 0, 0);
      __builtin_amdgcn_s_setprio(0);
    }
    __syncthreads();
    buf = nb;
  }
  int gq = l >> 4;
  int lodd = c0 & 1;
#pragma unroll
  for (int m = 0; m < 4; m++) {
#pragma unroll
    for (int i = 0; i < 4; i++) {
      int row = bm + m * 16 + gq * 4 + i;
      int b = row >> 11, tok = row & (NN - 1);
#pragma unroll
      for (int n = 0; n < 2; n++) {
        int col = bn + wc + n * 16 + c0;
        float val = acc[m][n][i];
        float partner = __shfl_xor(val, 1);
        if (bn < 1024) {
          int head = col >> 6, d = col & 63, j = d >> 1;
          float c = cosb[tok * 32 + j], s = sinb[tok * 32 + j];
          float r = lodd ? (partner * s + val * c) : (val * c - partner * s);
          qb[(((size_t)(b * NH + head)) * NN + tok) * 64 + d] = f2bf(r * QS);
        } else if (bn < 1280) {
          int cc = col - 1024;
          int kvh = cc >> 6, d = cc & 63, j = d >> 1;
          float c = cosb[tok * 32 + j], s = sinb[tok * 32 + j];
          float r = lodd ? (partner * s + val * c) : (val * c - partner * s);
          kb[(((size_t)(b * NKV + kvh)) * NN + tok) * 64 + d] = f2bf(r);
        } else {
          int cc = col - 1280;
          int kvh = cc >> 6, d = cc & 63;
          vtb[(((size_t)(b * NKV + kvh)) * 64 + d) * NN + tok] = f2bf(val);
        }
      }
    }
  }
}

// ---------------- fused FFN13 v5 (r11 champion): 128x64, BK=64, 2D-rect XCD ----------
// grid MUST be (42, 32). Rect per XCD = 21bx x 8by, bx-outer/by-inner.
__global__ __launch_bounds__(256, 2) void gemm_ffn13(
    const unsigned short* __restrict__ A, const unsigned short* __restrict__ B1t,
    const unsigned short* __restrict__ B3t, unsigned short* __restrict__ G,
    int Nc, int K) {
  __shared__ __align__(16) unsigned short Asm[2][128 * 64];
  __shared__ __align__(16) unsigned short B1sm[2][64 * 64];
  __shared__ __align__(16) unsigned short B3sm[2][64 * 64];
  int tid = threadIdx.x;
  int w = tid >> 6, l = tid & 63;
  // 2D-rect XCD map: 8 rects of 21x8 (2 x-rects, 4 y-rects), bx-outer/by-inner
  int bid = (int)blockIdx.y * gridDim.x + (int)blockIdx.x;
  int xcd = bid & 7, rr = bid >> 3;          // rr in [0,168)
  int bx = (xcd & 1) * 21 + (rr >> 3);
  int by = (xcd >> 1) * 8 + (rr & 7);
  int bm = by * 128, bn = bx * 64;
  int wr = (w >> 1) * 64, wc = (w & 1) * 32;
  int c0 = l & 15, g = l >> 4;

  // staging: wave w -> A rows [w*32,+32) (4 glds), B1/B3 rows [w*16,+16) (2 glds each)
  int lr = l >> 3;
  int sch = ((l & 7) ^ lr) * 8;
  const unsigned short* gA  = A + (size_t)(bm + w * 32 + lr) * K + sch;
  const unsigned short* gB1 = B1t + (size_t)(bn + w * 16 + lr) * K + sch;
  const unsigned short* gB3 = B3t + (size_t)(bn + w * 16 + lr) * K + sch;
  int lsA = (w * 32) * 64, lsB = (w * 16) * 64;

  f32x4 a1[4][2] = {};
  f32x4 a3[4][2] = {};
  int T = K / 64;
  glds16(gA, &Asm[0][lsA]);
  glds16(gA + 8 * K, &Asm[0][lsA + 8 * 64]);
  glds16(gA + 16 * K, &Asm[0][lsA + 16 * 64]);
  glds16(gA + 24 * K, &Asm[0][lsA + 24 * 64]);
  glds16(gB1, &B1sm[0][lsB]);
  glds16(gB1 + 8 * K, &B1sm[0][lsB + 8 * 64]);
  glds16(gB3, &B3sm[0][lsB]);
  glds16(gB3 + 8 * K, &B3sm[0][lsB + 8 * 64]);
  __syncthreads();
  int buf = 0;
  for (int s = 0; s < T; ++s) {
    int nb = buf ^ 1;
    if (s + 1 < T) {
      int ko = (s + 1) * 64;
      glds16(gA + ko, &Asm[nb][lsA]);
      glds16(gA + 8 * K + ko, &Asm[nb][lsA + 8 * 64]);
      glds16(gA + 16 * K + ko, &Asm[nb][lsA + 16 * 64]);
      glds16(gA + 24 * K + ko, &Asm[nb][lsA + 24 * 64]);
      glds16(gB1 + ko, &B1sm[nb][lsB]);
      glds16(gB1 + 8 * K + ko, &B1sm[nb][lsB + 8 * 64]);
      glds16(gB3 + ko, &B3sm[nb][lsB]);
      glds16(gB3 + 8 * K + ko, &B3sm[nb][lsB + 8 * 64]);
    }
    const unsigned short* As = Asm[buf];
    const unsigned short* B1s = B1sm[buf];
    const unsigned short* B3s = B3sm[buf];
#pragma unroll
    for (int ks = 0; ks < 2; ++ks) {
      short8 af[4], b1f[2], b3f[2];
#pragma unroll
      for (int m = 0; m < 4; m++) {
        int ra = wr + m * 16 + c0;
        af[m] = *(const short8*)&As[ra * 64 + (((ks * 4 + g) ^ (ra & 7)) * 8)];
      }
#pragma unroll
      for (int n = 0; n < 2; n++) {
        int rb = wc + n * 16 + c0;
        b1f[n] = *(const short8*)&B1s[rb * 64 + (((ks * 4 + g) ^ (rb & 7)) * 8)];
        b3f[n] = *(const short8*)&B3s[rb * 64 + (((ks * 4 + g) ^ (rb & 7)) * 8)];
      }
      __builtin_amdgcn_s_setprio(1);
#pragma unroll
      for (int m = 0; m < 4; m++)
#pragma unroll
        for (int n = 0; n < 2; n++) {
          a1[m][n] = __builtin_amdgcn_mfma_f32_16x16x32_bf16(af[m], b1f[n], a1[m][n], 0, 0, 0);
          a3[m][n] = __builtin_amdgcn_mfma_f32_16x16x32_bf16(af[m], b3f[n], a3[m][n], 0, 0, 0);
        }
      __builtin_amdgcn_s_setprio(0);
    }
    __syncthreads();
    buf = nb;
  }
  int gq = l >> 4;
#pragma unroll
  for (int m = 0; m < 4; m++) {
#pragma unroll
    for (int i = 0; i < 4; i++) {
      int row = bm + wr + m * 16 + gq * 4 + i;
#pragma unroll
      for (int n = 0; n < 2; n++) {
        int col = bn + wc + n * 16 + c0;
        float x1 = a1[m][n][i], x3 = a3[m][n][i];
        float sg = x1 / (1.0f + __expf(-x1));
        G[(size_t)row * Nc + col] = f2bf(sg * x3);
      }
    }
  }
}

// ---------------- flash attention v5: exp2 domain + defer-max (T13) ----------------
__global__ __launch_bounds__(256, 3) void attn_k(
    const unsigned short* __restrict__ qg_, const unsigned short* __restrict__ kg_,
    const unsigned short* __restrict__ vg_, unsigned short* __restrict__ ob) {
  __shared__ __align__(16) unsigned short Ksm[2][64 * 64];
  __shared__ __align__(16) unsigned short Vsm[2][64 * 64];
  int qb = (blockIdx.z == 0) ? (int)blockIdx.x : ((int)gridDim.x - 1 - (int)blockIdx.x);
  int h = blockIdx.y, b = blockIdx.z;
  int kvh = h & 3;  // jnp.tile semantics
  int tid = threadIdx.x, w = tid >> 6, l = tid & 63;
  int q5 = l & 31, hi = l >> 5;
  int qwbase = qb * 128 + w * 32;
  int qgl = qwbase + q5;

  const unsigned short* Kg = kg_ + ((size_t)(b * NKV + kvh)) * NN * 64;
  const unsigned short* Vg = vg_ + ((size_t)(b * NKV + kvh)) * 64 * NN;

  short8 qf[4];
  {
    const unsigned short* qrow = qg_ + (((size_t)(b * NH + h)) * NN + qgl) * 64 + hi * 8;
#pragma unroll
    for (int d = 0; d < 4; d++) qf[d] = *(const short8*)(qrow + d * 16);
  }

  int srow = l >> 3;
  int schunk = (l & 7) ^ (srow & 7);
  const unsigned short* gK = Kg + (size_t)(w * 16 + srow) * 64 + schunk * 8;
  const unsigned short* gV = Vg + (size_t)(w * 16 + srow) * NN + schunk * 8;

  int nkt = qb * 2 + 2;
  int nkt_w = ((qwbase + 31) >> 6) + 1;

  f32x16 O0 = {}, O1 = {};
  float m_r = -1e30f, l_r = 0.0f;

  glds16(gK, &Ksm[0][w * 1024]);
  glds16(gK + 8 * 64, &Ksm[0][w * 1024 + 512]);
  glds16(gV, &Vsm[0][w * 1024]);
  glds16(gV + 8 * NN, &Vsm[0][w * 1024 + 512]);
  __syncthreads();

  int buf = 0;
  for (int kt = 0; kt < nkt; ++kt) {
    int n0 = kt * 64;
    if (kt + 1 < nkt) {
      int nb = buf ^ 1;
      glds16(gK + (size_t)(n0 + 64) * 64, &Ksm[nb][w * 1024]);
      glds16(gK + (size_t)(n0 + 64) * 64 + 8 * 64, &Ksm[nb][w * 1024 + 512]);
      glds16(gV + n0 + 64, &Vsm[nb][w * 1024]);
      glds16(gV + 8 * NN + n0 + 64, &Vsm[nb][w * 1024 + 512]);
    }
    if (kt < nkt_w) {
      const unsigned short* Ks = Ksm[buf];
      const unsigned short* Vs = Vsm[buf];
      f32x16 S[2];
      __builtin_amdgcn_s_setprio(1);
#pragma unroll
      for (int s = 0; s < 2; s++) {
        f32x16 acc = {};
        int row = s * 32 + q5;
#pragma unroll
        for (int d = 0; d < 4; d++) {
          int ch = (2 * d + hi) ^ (row & 7);
          short8 kf = *(const short8*)&Ks[row * 64 + ch * 8];
          acc = __builtin_amdgcn_mfma_f32_32x32x16_bf16(kf, qf[d], acc, 0, 0, 0);
        }
        S[s] = acc;
      }
      __builtin_amdgcn_s_setprio(0);
      if (kt == nkt_w - 1) {
#pragma unroll
        for (int s = 0; s < 2; s++)
#pragma unroll
          for (int r = 0; r < 16; r++) {
            int kg = n0 + s * 32 + CROW(r, hi);
            S[s][r] = (kg > qgl) ? -1e30f : S[s][r];
          }
      }
      float t16[16];
#pragma unroll
      for (int r = 0; r < 16; r++) t16[r] = fmaxf(S[0][r], S[1][r]);
#pragma unroll
      for (int k = 8; k >= 1; k >>= 1)
#pragma unroll
        for (int r = 0; r < k; r++) t16[r] = fmaxf(t16[r], t16[r + k]);
      float pm = fmaxf(t16[0], __shfl_xor(t16[0], 32));
      if (!__all(pm <= m_r + 8.0f)) {
        float mn = fmaxf(m_r, pm);
        float alpha = exp2f(m_r - mn);
        m_r = mn;
        l_r *= alpha;
        float ab[16];
#pragma unroll
        for (int r = 0; r < 16; r++) ab[r] = __shfl(alpha, CROW(r, 0) + 4 * hi);
#pragma unroll
        for (int r = 0; r < 16; r++) { O0[r] *= ab[r]; O1[r] *= ab[r]; }
      }
#pragma unroll
      for (int s = 0; s < 2; s++)
#pragma unroll
        for (int r = 0; r < 16; r++) S[s][r] = exp2f(S[s][r] - m_r);
      float u[16];
#pragma unroll
      for (int r = 0; r < 16; r++) u[r] = S[0][r] + S[1][r];
#pragma unroll
      for (int k = 8; k >= 1; k >>= 1)
#pragma unroll
        for (int r = 0; r < k; r++) u[r] += u[r + k];
      l_r += (u[0] + __shfl_xor(u[0], 32));
      short8 paf[4];
#pragma unroll
      for (int ks = 0; ks < 4; ks++) {
        const int s = ks >> 1, e = ks & 1;
        unsigned a0, a1, b0, b1;
        asm("v_cvt_pk_bf16_f32 %0, %1, %2" : "=v"(a0) : "v"(S[s][8*e+0]), "v"(S[s][8*e+1]));
        asm("v_cvt_pk_bf16_f32 %0, %1, %2" : "=v"(a1) : "v"(S[s][8*e+2]), "v"(S[s][8*e+3]));
        asm("v_cvt_pk_bf16_f32 %0, %1, %2" : "=v"(b0) : "v"(S[s][8*e+4]), "v"(S[s][8*e+5]));
        asm("v_cvt_pk_bf16_f32 %0, %1, %2" : "=v"(b1) : "v"(S[s][8*e+6]), "v"(S[s][8*e+7]));
        asm("v_permlane32_swap_b32 %0, %1" : "+v"(a0), "+v"(b0));
        asm("v_permlane32_swap_b32 %0, %1" : "+v"(a1), "+v"(b1));
        union { unsigned u4[4]; short8 s8; } pk;
        pk.u4[0] = a0; pk.u4[1] = a1; pk.u4[2] = b0; pk.u4[3] = b1;
        paf[ks] = pk.s8;
      }
      __builtin_amdgcn_s_setprio(1);
#pragma unroll
      for (int ks = 0; ks < 4; ks++) {
        int row0 = q5, row1 = 32 + q5;
        short8 vf0 = *(const short8*)&Vs[row0 * 64 + (((2 * ks + hi) ^ (row0 & 7)) * 8)];
        short8 vf1 = *(const short8*)&Vs[row1 * 64 + (((2 * ks + hi) ^ (row1 & 7)) * 8)];
        O0 = __builtin_amdgcn_mfma_f32_32x32x16_bf16(paf[ks], vf0, O0, 0, 0, 0);
        O1 = __builtin_amdgcn_mfma_f32_32x32x16_bf16(paf[ks], vf1, O1, 0, 0, 0);
      }
      __builtin_amdgcn_s_setprio(0);
    }
    __syncthreads();
    buf ^= 1;
  }
  float linv = 1.0f / l_r;
  float lb[16];
#pragma unroll
  for (int r = 0; r < 16; r++) lb[r] = __shfl(linv, CROW(r, 0) + 4 * hi);
#pragma unroll
  for (int r = 0; r < 16; r++) {
    int orow = qwbase + CROW(r, hi);
    size_t base = ((size_t)b * NN + orow) * 1024 + h * 64 + q5;
    ob[base] = f2bf(O0[r] * lb[r]);
    ob[base + 32] = f2bf(O1[r] * lb[r]);
  }
}

// ---------------- launcher ----------------
extern "C" void kernel_launch(void* const* d_in, const int* in_sizes, int n_in,
                              void* d_out, int out_size, void* d_ws, size_t ws_size,
                              hipStream_t stream) {
  (void)in_sizes; (void)n_in; (void)out_size; (void)ws_size;
  const float* x    = (const float*)d_in[0];
  const float* w_an = (const float*)d_in[1];
  const float* w_fn = (const float*)d_in[2];
  const float* Wq   = (const float*)d_in[3];
  const float* Wkv  = (const float*)d_in[4];
  const float* Wo   = (const float*)d_in[5];
  const float* W1   = (const float*)d_in[6];
  const float* W2   = (const float*)d_in[7];
  const float* W3   = (const float*)d_in[8];
  const float* cosb = (const float*)d_in[9];
  const float* sinb = (const float*)d_in[10];
  float* out = (float*)d_out;

  char* ws = (char*)d_ws;
  size_t off = 0;
  auto take = [&](size_t bytes) {
    size_t r = off;
    off += (bytes + 255) & ~(size_t)255;
    return r;
  };
  unsigned short* WqkvT = (unsigned short*)(ws + take((size_t)1536 * 1024 * 2));
  unsigned short* WoT   = (unsigned short*)(ws + take((size_t)1024 * 1024 * 2));
  unsigned short* W1T   = (unsigned short*)(ws + take((size_t)2688 * 1024 * 2));
  unsigned short* W3T   = (unsigned short*)(ws + take((size_t)2688 * 1024 * 2));
  unsigned short* W2T   = (unsigned short*)(ws + take((size_t)2688 * 1024 * 2));
  unsigned short* hA    = (unsigned short*)(ws + take((size_t)MM * DIM * 2));  // reused as h2
  unsigned short* gbuf  = (unsigned short*)(ws + take((size_t)MM * INTER * 2));
  unsigned short* qbuf = (unsigned short*)(ws + take((size_t)MM * DIM * 2));
  unsigned short* kbuf = (unsigned short*)(ws + take((size_t)BB * NKV * NN * HD * 2));
  unsigned short* vtb  = (unsigned short*)(ws + take((size_t)BB * NKV * NN * HD * 2));
  unsigned short* obuf = (unsigned short*)(ws + take((size_t)MM * DIM * 2));
  unsigned short* x2b  = (unsigned short*)(ws + take((size_t)MM * DIM * 2));

  transpose_all<<<10624, 256, 0, stream>>>(Wq, Wkv, Wo, W1, W3, W2,
                                           WqkvT, WoT, W1T, W3T, W2T);
  rmsnorm_k<float><<<MM, 256, 0, stream>>>(x, w_an, hA);
  gemm_qkv<<<dim3(1536 / 128, MM / 64), 256, 0, stream>>>(hA, WqkvT, cosb, sinb,
                                                          qbuf, kbuf, vtb);
  attn_k<<<dim3(NN / 128, NH, BB), 256, 0, stream>>>(qbuf, kbuf, vtb, obuf);
  // x2 (bf16) = x + o @ Wo
  gemm64<float, unsigned short><<<dim3(1024 / 128, MM / 64), 256, 0, stream>>>(
      obuf, WoT, x, x2b, 1024, 1024);
  rmsnorm_k<unsigned short><<<MM, 256, 0, stream>>>(x2b, w_fn, hA);
  gemm_ffn13<<<dim3(INTER / 64, MM / 128), 256, 0, stream>>>(hA, W1T, W3T, gbuf, INTER, 1024);
  // out (fp32) = x2 + g @ W2
  gemm64<unsigned short, float><<<dim3(1024 / 128, MM / 64), 256, 0, stream>>>(
      gbuf, W2T, x2b, out, 1024, 2688);
}